// Round 7
// baseline (121.137 us; speedup 1.0000x reference)
//
#include <hip/hip_runtime.h>

#define BINS 256
#define EMBV 64          // EMB/4 float4s per row
#define BH   8           // 2*4 flattened batch

typedef float f32x4 __attribute__((ext_vector_type(4)));

// out[bh][i][j][d] = (s_i+s_j)*0.5 + s_i*s_j + T[|i-j|][d]
//
// Diagnostic round: 8-row register tile. Block = (bh, i-tile of 8 rows),
// si[0..7] register-resident; per 8-wide j-step each thread loads 1 sj +
// 8 tv (9 independent loads in flight) and issues 8 contiguous 1KiB
// wave-stores. Logical read traffic drops 2.0 -> ~0.36 B per output byte
// (sj amortized 8x, tab rows shared across waves via L1).
// XCD-grouped mapping kept: bh = blk&7 -> one bh (512KB read set) per XCD.
// Grid 256 blocks (1/CU, 32/XCD), 512 threads: d4 = t&63, tj = t>>6.
__global__ __launch_bounds__(512) void outputhead_kernel(
        const f32x4* __restrict__ seq4,   // [BH][BINS][EMBV]
        const f32x4* __restrict__ tab4,   // [256][EMBV]
        f32x4* __restrict__ out4)         // [BH][BINS][BINS][EMBV]
{
    const int blk = blockIdx.x;
    const int bh  = blk & 7;            // XCD-grouped: one bh per XCD
    const int it  = blk >> 3;           // 0..31 i-tile
    const int i0  = it * 8;
    const int t   = threadIdx.x;
    const int d4  = t & 63;
    const int tj  = t >> 6;             // 0..7 j sub-slot

    const size_t seq_bh_base = (size_t)bh * BINS * EMBV;

    f32x4 si[8];
    #pragma unroll
    for (int r = 0; r < 8; ++r)
        si[r] = seq4[seq_bh_base + (size_t)(i0 + r) * EMBV + d4];

    const size_t out_base = ((size_t)(bh * BINS + i0)) * BINS * EMBV;

    for (int jb = 0; jb < BINS; jb += 8) {
        const int j = jb + tj;

        const f32x4 sj = seq4[seq_bh_base + (size_t)j * EMBV + d4];

        f32x4 tv[8];
        #pragma unroll
        for (int r = 0; r < 8; ++r) {
            const int i    = i0 + r;
            const int dist = (i > j) ? (i - j) : (j - i);
            tv[r] = tab4[(size_t)dist * EMBV + d4];
        }

        #pragma unroll
        for (int r = 0; r < 8; ++r) {
            const f32x4 o = (si[r] + sj) * 0.5f + si[r] * sj + tv[r];
            out4[out_base + ((size_t)r * BINS + j) * EMBV + d4] = o;
        }
    }
}

extern "C" void kernel_launch(void* const* d_in, const int* in_sizes, int n_in,
                              void* d_out, int out_size, void* d_ws, size_t ws_size,
                              hipStream_t stream) {
    const f32x4* seq4 = (const f32x4*)d_in[0];  // (2,4,256,256) fp32
    const f32x4* tab4 = (const f32x4*)d_in[1];  // (256,256) fp32
    f32x4* out4 = (f32x4*)d_out;                // (2,4,256,256,256) fp32

    dim3 grid(BH * 32);    // 256 blocks: 8 bh x 32 i-tiles
    dim3 block(512);
    outputhead_kernel<<<grid, block, 0, stream>>>(seq4, tab4, out4);
}

// Round 8
// 97.404 us; speedup vs baseline: 1.2436x; 1.2436x over previous
//
#include <hip/hip_runtime.h>

#define BINS 256
#define EMBV 64          // EMB/4 float4s per row
#define BH   8           // 2*4 flattened batch

typedef float f32x4 __attribute__((ext_vector_type(4)));

// out[bh][i][j][d] = (s_i+s_j)*0.5 + s_i*s_j + T[|i-j|][d]
//
// R4 structure (98.2us: one block per (bh,i), XCD-grouped bh=blk&7) with ONE
// change: per-wave contiguous j-ranges. Wave tj owns j in [tj*64, tj*64+64),
// so each wave's store stream is a perfectly sequential 64KB run (DRAM
// page-local, robust to wave drift), instead of 1KiB pieces strided 4KiB
// apart. Loads unchanged: sj/tab rows are wave-uniform 1KiB L2-hit lines.
__global__ __launch_bounds__(256) void outputhead_kernel(
        const f32x4* __restrict__ seq4,   // [BH][BINS][EMBV]
        const f32x4* __restrict__ tab4,   // [256][EMBV]
        f32x4* __restrict__ out4)         // [BH][BINS][BINS][EMBV]
{
    const int blk = blockIdx.x;
    const int bh  = blk & 7;           // XCD-grouped: one bh per XCD
    const int i   = blk >> 3;          // consecutive same-XCD blocks -> adjacent i
    const int t   = threadIdx.x;
    const int d4  = t & 63;
    const int tj  = t >> 6;            // wave id 0..3 -> j quarter

    const f32x4 si = seq4[(bh * BINS + i) * EMBV + d4];

    const size_t seq_bh_base  = (size_t)bh * BINS * EMBV;
    const size_t out_row_base = ((size_t)(bh * BINS + i)) * BINS * EMBV;

    const int jbase = tj * 64;

    #pragma unroll 4
    for (int jo = 0; jo < 64; ++jo) {
        const int j    = jbase + jo;
        const int dist = (i > j) ? (i - j) : (j - i);

        const f32x4 sj = seq4[seq_bh_base + (size_t)j * EMBV + d4];
        const f32x4 tv = tab4[(size_t)dist * EMBV + d4];

        const f32x4 o = (si + sj) * 0.5f + si * sj + tv;

        out4[out_row_base + (size_t)j * EMBV + d4] = o;
    }
}

extern "C" void kernel_launch(void* const* d_in, const int* in_sizes, int n_in,
                              void* d_out, int out_size, void* d_ws, size_t ws_size,
                              hipStream_t stream) {
    const f32x4* seq4 = (const f32x4*)d_in[0];  // (2,4,256,256) fp32
    const f32x4* tab4 = (const f32x4*)d_in[1];  // (256,256) fp32
    f32x4* out4 = (f32x4*)d_out;                // (2,4,256,256,256) fp32

    dim3 grid(BH * BINS);   // 2048 blocks
    dim3 block(256);
    outputhead_kernel<<<grid, block, 0, stream>>>(seq4, tab4, out4);
}